// Round 1
// 106.570 us; speedup vs baseline: 1.0783x; 1.0783x over previous
//
#include <hip/hip_runtime.h>
#include <math.h>

#define BB 64
#define WW 128   // K (input feature dim per node)
#define FF 64    // nodes
#define HH 4
#define OW 128   // D (per-head output dim)

// ---------------------------------------------------------------------------
// Fully fused GAT: one block per (b,h), 512 threads, ZERO workspace use.
// The 256 MiB workspace poison fill (44 µs at HBM roofline) dominated the old
// timed window; this version never touches d_ws. Head-mean is done with
// coalesced atomicAdd into d_out, which is zeroed by hipMemsetAsync first.
//
// Phases (all LDS-resident, union-aliased regions, 92 KB total):
//   A) fs/fd projection GEMM, K split in 4 quarters of 32 (W staged 32 KB at
//      a time), 4i x 8d register tile per thread, acc kept in VGPRs.
//   B) epilogue: acc+bias -> fsl/fdl [64][132] (pad 132: b128-floor reads)
//   C) cs_i / cd_j:  score[i][j] = cs_i + cd_j + sum_d 0.4 a_d |fs+fd|
//      (LeakyReLU(s) = 0.6 s + 0.4 |s| for slope 0.2)
//   D) scores: wave w covers 8 j, lane = i  (fdv/B4 reads wave-uniform bcast)
//   E) softmax over i per j (8 strips), invl = 0.25/l (head mean folded)
//   F) aggregation: thread = (j = t&63, dblk = t>>6), 16 d each;
//      atomicAdd rows of 64 consecutive j -> fully coalesced 256B segments.
// ---------------------------------------------------------------------------

struct GemmRegion {
    float xq[32 * 64];         // [k quarter][i]
    float wq[2 * 128 * 36];    // [m][d][k quarter], row pad 36 (16B aligned)
};
struct AttnRegion {
    float fsl[64 * 132];       // [i][d] pad 132
    float fdl[64 * 132];       // [j][d] pad 132
    float st[64 * 68];         // [i][j] pad 68
    float A6[OW], B4[OW];      // 0.6*a_d, 0.4*a_d
    float cs[FF], cd[FF];
    float redm[8 * 64];        // [strip][j]
    float reds[8 * 64];
    float invl[64];
};
union SMem { GemmRegion g; AttnRegion a; };

__global__ __launch_bounds__(512) void gat_fused(
    const float* __restrict__ x,     // [B][128 k][64 i]
    const float* __restrict__ Wsrc,  // [512][128]
    const float* __restrict__ bsrc,
    const float* __restrict__ Wdst,
    const float* __restrict__ bdst,
    const float* __restrict__ attn,  // [H][128]
    float* __restrict__ out)         // [B][128 d][64 j], pre-zeroed
{
    __shared__ __align__(16) SMem sm;
    __shared__ float bl[2 * 128];    // bias, outside the union (live in both)

    const int bx = blockIdx.x;
    const int h  = bx & 3;
    const int b  = bx >> 2;
    const int t  = threadIdx.x;

    // ------------------- phase A: projection GEMM ------------------------
    // thread tile: m = src/dst, 4 i, 8 d.  512 = 2 * 16 * 16 threads.
    const int m  = t >> 8;
    const int i0 = (t & 15) * 4;
    const int d0 = ((t >> 4) & 15) * 8;

    if (t < 256) bl[t] = (t & 128 ? bdst : bsrc)[h * 128 + (t & 127)];

    float acc[8][4] = {};            // [dd][ii]

    for (int kq = 0; kq < 4; ++kq) {
        if (kq) __syncthreads();
        // stage x quarter: [32 k][64 i] = 512 float4, fully coalesced
        {
            const float4* xs = (const float4*)(x + ((size_t)b * WW + kq * 32) * FF);
            ((float4*)sm.g.xq)[t] = xs[t];
        }
        // stage W quarter: 2 mats x 128 d x 8 quads = 2048 float4
        #pragma unroll
        for (int p = 0; p < 4; ++p) {
            int idx = p * 512 + t;
            int mm = idx >> 10, d = (idx >> 3) & 127, q = idx & 7;
            const float* src = (mm ? Wdst : Wsrc)
                             + (size_t)(h * 128 + d) * WW + kq * 32 + q * 4;
            *(float4*)&sm.g.wq[(mm * 128 + d) * 36 + q * 4] = *(const float4*)src;
        }
        __syncthreads();

        #pragma unroll
        for (int k0 = 0; k0 < 32; k0 += 4) {
            float4 xv[4];
            #pragma unroll
            for (int kk = 0; kk < 4; ++kk)
                xv[kk] = *(const float4*)&sm.g.xq[(k0 + kk) * 64 + i0];
            float4 wv[8];
            #pragma unroll
            for (int dd = 0; dd < 8; ++dd)
                wv[dd] = *(const float4*)&sm.g.wq[(m * 128 + d0 + dd) * 36 + k0];
            #pragma unroll
            for (int kk = 0; kk < 4; ++kk) {
                const float* xf = (const float*)&xv[kk];
                #pragma unroll
                for (int dd = 0; dd < 8; ++dd) {
                    const float wf = ((const float*)&wv[dd])[kk];
                    acc[dd][0] = fmaf(xf[0], wf, acc[dd][0]);
                    acc[dd][1] = fmaf(xf[1], wf, acc[dd][1]);
                    acc[dd][2] = fmaf(xf[2], wf, acc[dd][2]);
                    acc[dd][3] = fmaf(xf[3], wf, acc[dd][3]);
                }
            }
        }
    }
    __syncthreads();   // GEMM region dead; attn region may now be written

    // ------------- phase B: acc+bias -> fsl/fdl, stage A6/B4 -------------
    {
        float* dst = m ? sm.a.fdl : sm.a.fsl;
        #pragma unroll
        for (int ii = 0; ii < 4; ++ii) {
            #pragma unroll
            for (int dq = 0; dq < 2; ++dq) {
                float4 o;
                o.x = acc[dq * 4 + 0][ii] + bl[m * 128 + d0 + dq * 4 + 0];
                o.y = acc[dq * 4 + 1][ii] + bl[m * 128 + d0 + dq * 4 + 1];
                o.z = acc[dq * 4 + 2][ii] + bl[m * 128 + d0 + dq * 4 + 2];
                o.w = acc[dq * 4 + 3][ii] + bl[m * 128 + d0 + dq * 4 + 3];
                *(float4*)&dst[(i0 + ii) * 132 + d0 + dq * 4] = o;
            }
        }
        if (t < 128) {
            float av = attn[h * OW + t];
            sm.a.A6[t] = 0.6f * av;
            sm.a.B4[t] = 0.4f * av;
        }
    }
    __syncthreads();

    // ------------------- phase C: cs_i and cd_j --------------------------
    if (t < 64) {
        float s = 0.0f;
        #pragma unroll 8
        for (int c = 0; c < 32; ++c) {
            float4 fv = *(const float4*)&sm.a.fsl[t * 132 + c * 4];
            float4 av = *(const float4*)&sm.a.A6[c * 4];
            s = fmaf(fv.x, av.x, fmaf(fv.y, av.y, fmaf(fv.z, av.z, fmaf(fv.w, av.w, s))));
        }
        sm.a.cs[t] = s;
    } else if (t < 128) {
        const int j = t - 64;
        float s = 0.0f;
        #pragma unroll 8
        for (int c = 0; c < 32; ++c) {
            float4 fv = *(const float4*)&sm.a.fdl[j * 132 + c * 4];
            float4 av = *(const float4*)&sm.a.A6[c * 4];
            s = fmaf(fv.x, av.x, fmaf(fv.y, av.y, fmaf(fv.z, av.z, fmaf(fv.w, av.w, s))));
        }
        sm.a.cd[j] = s;
    }
    __syncthreads();

    // ------------------- phase D: scores ---------------------------------
    // wave (t>>6) covers 8 j; lane = i. fdv/B4 wave-uniform broadcasts.
    {
        const int lane = t & 63;
        const int jl0  = (t >> 6) * 8;
        float sc[8] = {};
        #pragma unroll 4
        for (int c = 0; c < 32; ++c) {
            const int dd0 = c * 4;
            float4 fsv = *(const float4*)&sm.a.fsl[lane * 132 + dd0];
            float4 b4  = *(const float4*)&sm.a.B4[dd0];
            #pragma unroll
            for (int jj = 0; jj < 8; ++jj) {
                float4 fdv = *(const float4*)&sm.a.fdl[(jl0 + jj) * 132 + dd0];
                float r = sc[jj];
                r = fmaf(b4.x, fabsf(fsv.x + fdv.x), r);
                r = fmaf(b4.y, fabsf(fsv.y + fdv.y), r);
                r = fmaf(b4.z, fabsf(fsv.z + fdv.z), r);
                r = fmaf(b4.w, fabsf(fsv.w + fdv.w), r);
                sc[jj] = r;
            }
        }
        const float csl = sm.a.cs[lane];
        float4 o0, o1;
        o0.x = sc[0] + csl + sm.a.cd[jl0 + 0];
        o0.y = sc[1] + csl + sm.a.cd[jl0 + 1];
        o0.z = sc[2] + csl + sm.a.cd[jl0 + 2];
        o0.w = sc[3] + csl + sm.a.cd[jl0 + 3];
        o1.x = sc[4] + csl + sm.a.cd[jl0 + 4];
        o1.y = sc[5] + csl + sm.a.cd[jl0 + 5];
        o1.z = sc[6] + csl + sm.a.cd[jl0 + 6];
        o1.w = sc[7] + csl + sm.a.cd[jl0 + 7];
        *(float4*)&sm.a.st[lane * 68 + jl0]     = o0;
        *(float4*)&sm.a.st[lane * 68 + jl0 + 4] = o1;
    }
    __syncthreads();

    // ------------------- phase E: softmax over i per j -------------------
    {
        const int j = t & 63, st8 = t >> 6;
        const int i0s = st8 * 8;
        float mx = sm.a.st[i0s * 68 + j];
        #pragma unroll
        for (int k = 1; k < 8; ++k) mx = fmaxf(mx, sm.a.st[(i0s + k) * 68 + j]);
        sm.a.redm[st8 * 64 + j] = mx;
    }
    __syncthreads();
    {
        const int j = t & 63, st8 = t >> 6;
        const int i0s = st8 * 8;
        float mj = sm.a.redm[j];
        #pragma unroll
        for (int s2 = 1; s2 < 8; ++s2) mj = fmaxf(mj, sm.a.redm[s2 * 64 + j]);
        float ps = 0.0f;
        #pragma unroll
        for (int k = 0; k < 8; ++k) {
            float e = __expf(sm.a.st[(i0s + k) * 68 + j] - mj);
            sm.a.st[(i0s + k) * 68 + j] = e;
            ps += e;
        }
        sm.a.reds[st8 * 64 + j] = ps;
    }
    __syncthreads();
    if (t < 64) {
        float l = 0.0f;
        #pragma unroll
        for (int s2 = 0; s2 < 8; ++s2) l += sm.a.reds[s2 * 64 + t];
        sm.a.invl[t] = 0.25f / l;            // head-mean folded in
    }
    __syncthreads();

    // ------------- phase F: aggregation + coalesced atomic out -----------
    // thread = (j = t&63, dblk = t>>6): 16 consecutive d per thread.
    // out[b][d][j]: for each e, the 64 lanes of a wave cover 64 consecutive
    // j -> contiguous 256B atomicAdd segments.
    {
        const int j = t & 63, dblk = t >> 6;
        float ag[16] = {};
        #pragma unroll 4
        for (int i = 0; i < FF; ++i) {
            const float p = sm.a.st[i * 68 + j];
            const float* fr = &sm.a.fsl[i * 132 + dblk * 16];
            float4 f0 = *(const float4*)(fr);
            float4 f1 = *(const float4*)(fr + 4);
            float4 f2 = *(const float4*)(fr + 8);
            float4 f3 = *(const float4*)(fr + 12);
            ag[0]  = fmaf(p, f0.x, ag[0]);  ag[1]  = fmaf(p, f0.y, ag[1]);
            ag[2]  = fmaf(p, f0.z, ag[2]);  ag[3]  = fmaf(p, f0.w, ag[3]);
            ag[4]  = fmaf(p, f1.x, ag[4]);  ag[5]  = fmaf(p, f1.y, ag[5]);
            ag[6]  = fmaf(p, f1.z, ag[6]);  ag[7]  = fmaf(p, f1.w, ag[7]);
            ag[8]  = fmaf(p, f2.x, ag[8]);  ag[9]  = fmaf(p, f2.y, ag[9]);
            ag[10] = fmaf(p, f2.z, ag[10]); ag[11] = fmaf(p, f2.w, ag[11]);
            ag[12] = fmaf(p, f3.x, ag[12]); ag[13] = fmaf(p, f3.y, ag[13]);
            ag[14] = fmaf(p, f3.z, ag[14]); ag[15] = fmaf(p, f3.w, ag[15]);
        }
        const float iv = sm.a.invl[j];
        float* ob = out + ((size_t)b * OW + dblk * 16) * FF + j;
        #pragma unroll
        for (int e = 0; e < 16; ++e)
            atomicAdd(ob + e * FF, ag[e] * iv);
    }
}

// ---------------------------------------------------------------------------
extern "C" void kernel_launch(void* const* d_in, const int* in_sizes, int n_in,
                              void* d_out, int out_size, void* d_ws, size_t ws_size,
                              hipStream_t stream) {
    const float* x    = (const float*)d_in[0];
    const float* Wsrc = (const float*)d_in[1];
    const float* bsrc = (const float*)d_in[2];
    const float* Wdst = (const float*)d_in[3];
    const float* bdst = (const float*)d_in[4];
    const float* attn = (const float*)d_in[5];

    // No workspace use at all (testing whether the 256 MiB ws poison fill
    // leaves the timed window). Zero out for the head-mean atomic adds.
    hipMemsetAsync(d_out, 0, (size_t)out_size, stream);
    gat_fused<<<BB * HH, 512, 0, stream>>>(x, Wsrc, bsrc, Wdst, bdst, attn,
                                           (float*)d_out);
}

// Round 2
// 105.149 us; speedup vs baseline: 1.0928x; 1.0135x over previous
//
#include <hip/hip_runtime.h>
#include <math.h>

#define BB 64
#define WW 128   // K (input feature dim per node)
#define FF 64    // nodes
#define HH 4
#define OW 128   // D (per-head output dim)

// ---------------------------------------------------------------------------
// Fully fused GAT, v2: 1024 threads/block (16 waves/CU = 4/SIMD, was 2/SIMD).
// Round-1 counters: Occupancy 18.7%, VALUBusy 43% -> latency-bound at 2
// waves/SIMD with 1 block/CU (90 KB LDS). Same grid (b,h)=256 blocks; total
// VALU work unchanged, per-thread work halved, stall exposure ~halved.
//
// Changes vs v1:
//  - 1024 threads; GEMM K staged in two 64-wide halves (2 stage barriers
//    instead of 4); per-thread tile 4i x 4d.
//  - d-group remap d0 = (g>>2)*16 + (g&3)*4: a wave's 4 simultaneous wq-row
//    reads are 4 rows apart (16c mod 32 = {0,16}) -> 2-way (free), killing
//    the v1 4-way conflict (8 rows apart, 8*36 = 0 mod 32 = same banks).
//  - phase C (cs/cd) parallelized to 256 threads via redm partials; cs/cd
//    summed at phase-D epilogue (one barrier + serial step removed).
//  - invl computed per-thread in phase F from reds strips (barrier removed).
// ---------------------------------------------------------------------------

struct GemmRegion {
    float xq[64 * 64];          // [k-half 64][i 64]        16 KB
    float wq[2 * 128 * 68];     // [(m*128+d)][k 64 pad 68] 69.6 KB
};
struct AttnRegion {
    float fsl[FF * 132];        // [i][d] pad 132
    float fdl[FF * 132];        // [j][d] pad 132
    float st[FF * 68];          // [i][j] pad 68
    float A6[OW], B4[OW];       // 0.6*a_d, 0.4*a_d
    float redm[16 * 64];        // strips / cs-cd partials
    float reds[16 * 64];
};
union SMem { GemmRegion g; AttnRegion a; };

__global__ __launch_bounds__(1024) void gat_fused(
    const float* __restrict__ x,     // [B][128 k][64 i]
    const float* __restrict__ Wsrc,  // [512][128]
    const float* __restrict__ bsrc,
    const float* __restrict__ Wdst,
    const float* __restrict__ bdst,
    const float* __restrict__ attn,  // [H][128]
    float* __restrict__ out)         // [B][128 d][64 j], pre-zeroed
{
    __shared__ __align__(16) SMem sm;
    __shared__ float bl[2 * 128];

    const int bx = blockIdx.x;
    const int h  = bx & 3;
    const int b  = bx >> 2;
    const int t  = threadIdx.x;

    // ------------------- phase A: projection GEMM ------------------------
    // 1024 = 2m x 16 i-groups x 32 d-groups; per-thread 4i x 4d.
    const int m  = t >> 9;
    const int i0 = (t & 15) * 4;
    const int g2 = (t >> 4) & 31;
    const int d0 = (g2 >> 2) * 16 + (g2 & 3) * 4;   // conflict-free remap

    if (t < 256) bl[t] = (t & 128 ? bdst : bsrc)[h * 128 + (t & 127)];

    float acc[4][4] = {};            // [e = d][ii = i]

    for (int kh = 0; kh < 2; ++kh) {
        if (kh) __syncthreads();
        // stage x half: [64 k][64 i] = 1024 float4, 1 per thread, coalesced
        {
            const int k = t >> 4, iq = t & 15;
            *(float4*)&sm.g.xq[k * 64 + iq * 4] =
                *(const float4*)(x + ((size_t)b * WW + kh * 64 + k) * FF + iq * 4);
        }
        // stage W half: 2 mats x 128 d x 16 quads = 4096 float4
        #pragma unroll
        for (int p = 0; p < 4; ++p) {
            const int idx = p * 1024 + t;
            const int mm = idx >> 11, d = (idx >> 4) & 127, q = idx & 15;
            *(float4*)&sm.g.wq[(mm * 128 + d) * 68 + q * 4] =
                *(const float4*)((mm ? Wdst : Wsrc)
                                 + (size_t)(h * 128 + d) * WW + kh * 64 + q * 4);
        }
        __syncthreads();

        #pragma unroll 4
        for (int k0 = 0; k0 < 64; k0 += 4) {
            float4 xv[4], wv[4];
            #pragma unroll
            for (int kk = 0; kk < 4; ++kk)
                xv[kk] = *(const float4*)&sm.g.xq[(k0 + kk) * 64 + i0];
            #pragma unroll
            for (int e = 0; e < 4; ++e)
                wv[e] = *(const float4*)&sm.g.wq[(m * 128 + d0 + e) * 68 + k0];
            #pragma unroll
            for (int kk = 0; kk < 4; ++kk) {
                #pragma unroll
                for (int e = 0; e < 4; ++e) {
                    const float wf = ((const float*)&wv[e])[kk];
                    const float* xf = (const float*)&xv[kk];
                    acc[e][0] = fmaf(xf[0], wf, acc[e][0]);
                    acc[e][1] = fmaf(xf[1], wf, acc[e][1]);
                    acc[e][2] = fmaf(xf[2], wf, acc[e][2]);
                    acc[e][3] = fmaf(xf[3], wf, acc[e][3]);
                }
            }
        }
    }
    __syncthreads();   // GEMM region dead; attn region may now be written

    // ------------- phase B: acc+bias -> fsl/fdl, stage A6/B4 -------------
    {
        float* dst = m ? sm.a.fdl : sm.a.fsl;
        const float b0 = bl[m * 128 + d0 + 0];
        const float b1 = bl[m * 128 + d0 + 1];
        const float b2 = bl[m * 128 + d0 + 2];
        const float b3 = bl[m * 128 + d0 + 3];
        #pragma unroll
        for (int ii = 0; ii < 4; ++ii) {
            float4 o;
            o.x = acc[0][ii] + b0;
            o.y = acc[1][ii] + b1;
            o.z = acc[2][ii] + b2;
            o.w = acc[3][ii] + b3;
            *(float4*)&dst[(i0 + ii) * 132 + d0] = o;
        }
        if (t < 128) {
            const float av = attn[h * OW + t];
            sm.a.A6[t] = 0.6f * av;
            sm.a.B4[t] = 0.4f * av;
        }
    }
    __syncthreads();

    // --------- phase C: cs/cd partials (256 threads, 2 halves each) ------
    // redm[sel*64+i]: sel 0,1 = fs halves; 2,3 = fd halves. Summed in D.
    if (t < 256) {
        const int i = t & 63, sel = t >> 6;
        const float* src = (sel < 2 ? sm.a.fsl : sm.a.fdl) + i * 132 + (sel & 1) * 64;
        const float* a6  = sm.a.A6 + (sel & 1) * 64;
        float s = 0.0f;
        #pragma unroll
        for (int c = 0; c < 16; ++c) {
            float4 fv = *(const float4*)&src[c * 4];
            float4 av = *(const float4*)&a6[c * 4];
            s = fmaf(fv.x, av.x, fmaf(fv.y, av.y, fmaf(fv.z, av.z, fmaf(fv.w, av.w, s))));
        }
        sm.a.redm[sel * 64 + i] = s;
    }
    __syncthreads();

    // ------------------- phase D: scores ---------------------------------
    // wave (t>>6) covers 4 j; lane = i. fdv/B4 reads wave-uniform bcast.
    {
        const int lane = t & 63;
        const int jl0  = (t >> 6) * 4;
        float sc[4] = {};
        #pragma unroll 8
        for (int c = 0; c < 32; ++c) {
            const int dd0 = c * 4;
            float4 fsv = *(const float4*)&sm.a.fsl[lane * 132 + dd0];
            float4 b4  = *(const float4*)&sm.a.B4[dd0];
            #pragma unroll
            for (int jj = 0; jj < 4; ++jj) {
                float4 fdv = *(const float4*)&sm.a.fdl[(jl0 + jj) * 132 + dd0];
                float r = sc[jj];
                r = fmaf(b4.x, fabsf(fsv.x + fdv.x), r);
                r = fmaf(b4.y, fabsf(fsv.y + fdv.y), r);
                r = fmaf(b4.z, fabsf(fsv.z + fdv.z), r);
                r = fmaf(b4.w, fabsf(fsv.w + fdv.w), r);
                sc[jj] = r;
            }
        }
        const float csl = sm.a.redm[lane] + sm.a.redm[64 + lane];
        float4 o;
        o.x = sc[0] + csl + sm.a.redm[128 + jl0 + 0] + sm.a.redm[192 + jl0 + 0];
        o.y = sc[1] + csl + sm.a.redm[128 + jl0 + 1] + sm.a.redm[192 + jl0 + 1];
        o.z = sc[2] + csl + sm.a.redm[128 + jl0 + 2] + sm.a.redm[192 + jl0 + 2];
        o.w = sc[3] + csl + sm.a.redm[128 + jl0 + 3] + sm.a.redm[192 + jl0 + 3];
        *(float4*)&sm.a.st[lane * 68 + jl0] = o;
    }
    __syncthreads();

    // ------------------- phase E: softmax over i per j -------------------
    {   // E1: per-strip max (16 strips of 4 i)
        const int j = t & 63, s = t >> 6;
        const int i0s = s * 4;
        float mx = sm.a.st[i0s * 68 + j];
        #pragma unroll
        for (int k = 1; k < 4; ++k) mx = fmaxf(mx, sm.a.st[(i0s + k) * 68 + j]);
        sm.a.redm[s * 64 + j] = mx;
    }
    __syncthreads();
    {   // E2: global max, exp in place, per-strip sum
        const int j = t & 63, s = t >> 6;
        const int i0s = s * 4;
        float mj = sm.a.redm[j];
        #pragma unroll
        for (int s2 = 1; s2 < 16; ++s2) mj = fmaxf(mj, sm.a.redm[s2 * 64 + j]);
        float ps = 0.0f;
        #pragma unroll
        for (int k = 0; k < 4; ++k) {
            float e = __expf(sm.a.st[(i0s + k) * 68 + j] - mj);
            sm.a.st[(i0s + k) * 68 + j] = e;
            ps += e;
        }
        sm.a.reds[s * 64 + j] = ps;
    }
    __syncthreads();

    // ------------- phase F: aggregation + coalesced atomic out -----------
    // thread = (j = t&63, dblk = t>>6): 8 consecutive d per thread.
    {
        const int j = t & 63, dblk = t >> 6;
        float l = 0.0f;
        #pragma unroll
        for (int s2 = 0; s2 < 16; ++s2) l += sm.a.reds[s2 * 64 + j];
        const float iv = 0.25f / l;          // head-mean folded in

        float ag[8] = {};
        #pragma unroll 4
        for (int i = 0; i < FF; ++i) {
            const float p = sm.a.st[i * 68 + j];
            const float* fr = &sm.a.fsl[i * 132 + dblk * 8];
            float4 f0 = *(const float4*)(fr);
            float4 f1 = *(const float4*)(fr + 4);
            ag[0] = fmaf(p, f0.x, ag[0]);  ag[1] = fmaf(p, f0.y, ag[1]);
            ag[2] = fmaf(p, f0.z, ag[2]);  ag[3] = fmaf(p, f0.w, ag[3]);
            ag[4] = fmaf(p, f1.x, ag[4]);  ag[5] = fmaf(p, f1.y, ag[5]);
            ag[6] = fmaf(p, f1.z, ag[6]);  ag[7] = fmaf(p, f1.w, ag[7]);
        }
        float* ob = out + ((size_t)b * OW + dblk * 8) * FF + j;
        #pragma unroll
        for (int e = 0; e < 8; ++e)
            atomicAdd(ob + e * FF, ag[e] * iv);
    }
}

// ---------------------------------------------------------------------------
extern "C" void kernel_launch(void* const* d_in, const int* in_sizes, int n_in,
                              void* d_out, int out_size, void* d_ws, size_t ws_size,
                              hipStream_t stream) {
    const float* x    = (const float*)d_in[0];
    const float* Wsrc = (const float*)d_in[1];
    const float* bsrc = (const float*)d_in[2];
    const float* Wdst = (const float*)d_in[3];
    const float* bdst = (const float*)d_in[4];
    const float* attn = (const float*)d_in[5];

    hipMemsetAsync(d_out, 0, (size_t)out_size, stream);
    gat_fused<<<BB * HH, 1024, 0, stream>>>(x, Wsrc, bsrc, Wdst, bdst, attn,
                                            (float*)d_out);
}